// Round 17
// baseline (178.326 us; speedup 1.0000x reference)
//
#include <hip/hip_runtime.h>
#include <stdint.h>

typedef unsigned short u16;

// ---------- bf16 helpers ----------
__device__ __forceinline__ float b2f(u16 u) {
  union { uint32_t i; float f; } v; v.i = ((uint32_t)u) << 16; return v.f;
}
__device__ __forceinline__ u16 f2b(float f) {
  union { float f; uint32_t i; } v; v.f = f;
  uint32_t x = v.i;
  return (u16)((x + 0x7FFFu + ((x >> 16) & 1u)) >> 16);
}

// async global->LDS, 16B per lane; LDS dst is wave-uniform base + lane*16 (linear)
__device__ __forceinline__ void gload16(const void* g, void* l) {
  __builtin_amdgcn_global_load_lds(
      (const __attribute__((address_space(1))) void*)g,
      (__attribute__((address_space(3))) void*)l, 16, 0, 0);
}

typedef __attribute__((ext_vector_type(8))) short short8v;
typedef __attribute__((ext_vector_type(4))) float f32x4;
typedef __attribute__((ext_vector_type(4))) u16 u16x4;

// ---------- fused prologue: init | prep | transposeW1 | transposeW2 | cvt ----------
__global__ __launch_bounds__(256) void k_misc(
    int* deg, uint32_t* padw, int n, int padwords,
    const float* __restrict__ b1, const float* __restrict__ g,
    const float* __restrict__ be, const float* __restrict__ mu,
    const float* __restrict__ var, const float* __restrict__ b2,
    const float* __restrict__ t, float* SC, float* TB, float* B2f, float* tf,
    int H, int D,
    const float* __restrict__ W1, u16* __restrict__ W1T,
    const float* __restrict__ W2, u16* __restrict__ W2T,
    const float* __restrict__ x, u16* __restrict__ xb, int n4,
    int nb_init, int nb_prep, int nb_t1, int nb_t2, int nb_cvt) {
  __shared__ u16 tile[32][33];
  int b = blockIdx.x;
  const int tid = threadIdx.x;

  if (b < nb_init) {  // zero deg + Apatch pad rows
    int i = b * 256 + tid;
    if (i < n) deg[i] = 0;
    if (i < padwords) padw[i] = 0u;
    return;
  }
  b -= nb_init;
  if (b < nb_prep) {  // BN fold + b2 + temperature (and t*log2e for exp2)
    int i = b * 256 + tid;
    if (i < H) {
      float sc = g[i] * rsqrtf(var[i] + 1e-5f);
      SC[i] = sc;
      TB[i] = (b1[i] - mu[i]) * sc + be[i];
    }
    if (i < D) B2f[i] = b2[i];
    if (i == 0) { tf[0] = t[0]; tf[1] = t[0] * 1.4426950408889634f; }
    return;
  }
  b -= nb_prep;
  if (b < nb_t1) {  // W1 [D][H] -> W1T [H][D] bf16
    const int nbx = H / 32;
    const int bx = (b % nbx) * 32, by = (b / nbx) * 32;
    const int tx = tid & 31, ty = tid >> 5;
    for (int i = 0; i < 32; i += 8)
      tile[ty + i][tx] = f2b(W1[(size_t)(by + ty + i) * H + bx + tx]);
    __syncthreads();
    for (int i = 0; i < 32; i += 8)
      W1T[(size_t)(bx + ty + i) * D + by + tx] = tile[tx][ty + i];
    return;
  }
  b -= nb_t1;
  if (b < nb_t2) {  // W2 [H][D] -> W2T [D][H] bf16
    const int nbx = D / 32;
    const int bx = (b % nbx) * 32, by = (b / nbx) * 32;
    const int tx = tid & 31, ty = tid >> 5;
    for (int i = 0; i < 32; i += 8)
      tile[ty + i][tx] = f2b(W2[(size_t)(by + ty + i) * D + bx + tx]);
    __syncthreads();
    for (int i = 0; i < 32; i += 8)
      W2T[(size_t)(bx + ty + i) * H + by + tx] = tile[tx][ty + i];
    return;
  }
  b -= nb_t2;
  {  // x fp32 -> xb bf16, grid-stride, float4/ushort4
    int i = b * 256 + tid;
    const int stride = nb_cvt * 256;
    for (; i < n4; i += stride) {
      f32x4 v = *(const f32x4*)(x + (size_t)i * 4);
      u16x4 o;
      o[0] = f2b(v[0]); o[1] = f2b(v[1]); o[2] = f2b(v[2]); o[3] = f2b(v[3]);
      *(u16x4*)(xb + (size_t)i * 4) = o;
    }
  }
}

// ---------- CSR build ----------
__global__ void k_hist(const int* __restrict__ ei, int* deg, int E) {
  int e = blockIdx.x * 256 + threadIdx.x;
  if (e < E) atomicAdd(&deg[ei[E + e]], 1);  // dst = ei[1][e]
}

// shuffle-based scan: 2 barriers instead of 20
__global__ void k_scan(const int* __restrict__ deg, int* rowptr, int* cursor, int n, int E) {
  __shared__ int wsum[16];
  const int tid = threadIdx.x;
  const int lane = tid & 63, wv = tid >> 6;
  const int CH = (n + 1023) / 1024;
  const int base = tid * CH;
  int s = 0;
  for (int i = 0; i < CH; ++i) {
    int idx = base + i;
    s += (idx < n) ? deg[idx] : 0;
  }
  int incl = s;
  for (int d2 = 1; d2 < 64; d2 <<= 1) {
    int t2 = __shfl_up(incl, d2);
    if (lane >= d2) incl += t2;
  }
  if (lane == 63) wsum[wv] = incl;
  __syncthreads();
  if (wv == 0) {
    int v = (lane < 16) ? wsum[lane] : 0;
    for (int d2 = 1; d2 < 16; d2 <<= 1) {
      int t2 = __shfl_up(v, d2);
      if (lane >= d2) v += t2;
    }
    if (lane < 16) wsum[lane] = v;
  }
  __syncthreads();
  int run = (wv ? wsum[wv - 1] : 0) + (incl - s);
  for (int i = 0; i < CH; ++i) {
    int idx = base + i;
    if (idx < n) {
      rowptr[idx] = run; cursor[idx] = run;
      run += deg[idx];
    }
  }
  if (tid == 1023) rowptr[n] = run;  // == E
}

__global__ void k_scatter(const int* __restrict__ ei, int* cursor, int* csr_src, int E) {
  int e = blockIdx.x * 256 + threadIdx.x;
  if (e < E) {
    int d = ei[E + e];
    int p = atomicAdd(&cursor[d], 1);
    csr_src[p] = ei[e];  // store src node id
  }
}

// ---------- XCD-channel-sliced gather + segment-softmax + aggregate + root add ----
// grid = n*8 blocks; cg = blockIdx & 7 binds a 96-channel slice to one XCD
// (HW round-robins consecutive blockIdx across XCDs). Each XCD's gather
// working set = n x 192 B = 1.92 MB -> L2-resident (4 MB/XCD), so the random
// src gathers become L2 hits instead of 8x-replicated L3/HBM traffic.
// Block = 192 threads = 4 edge-groups x 48 words; LDS cross-group reduce.
__global__ __launch_bounds__(192) void k_agg(const uint32_t* __restrict__ xw,
    const float* __restrict__ xf,
    const int* __restrict__ rowptr, const int* __restrict__ csr_src,
    const float* __restrict__ tf, uint32_t* __restrict__ abufw,
    uint32_t* __restrict__ Apatchw, int PB0, int D) {
  __shared__ float red[4][48][4];
  const int bid = blockIdx.x;
  const int nd = bid >> 3, cg = bid & 7;
  const int tid = threadIdx.x;
  const int WPS = D >> 4;            // 48 words per slice
  const int g = tid / WPS;           // edge-group 0..3
  const int w = tid - g * WPS;       // word in slice 0..47
  const float tl = tf[1];            // t * log2(e)
  const int beg = rowptr[nd], end = rowptr[nd + 1];
  const int Dw = D >> 1;             // 384 words per row
  const int wo = cg * WPS + w;       // word offset in row
  float d0 = 0.f, d1 = 0.f, n0 = 0.f, n1 = 0.f;
  for (int j = beg + g; j < end; j += 4) {
    const uint32_t u = xw[(size_t)csr_src[j] * Dw + wo];
    float lo = __uint_as_float(u << 16);
    float hi = __uint_as_float(u & 0xFFFF0000u);
    float g0 = fmaxf(lo, 0.f) + 1e-7f;
    float g1 = fmaxf(hi, 0.f) + 1e-7f;
    float e0 = __builtin_amdgcn_exp2f(g0 * tl);
    float e1 = __builtin_amdgcn_exp2f(g1 * tl);
    d0 += e0; n0 = fmaf(g0, e0, n0);
    d1 += e1; n1 = fmaf(g1, e1, n1);
  }
  red[g][w][0] = d0; red[g][w][1] = d1; red[g][w][2] = n0; red[g][w][3] = n1;
  __syncthreads();
  if (tid < WPS) {
    float D0 = red[0][tid][0] + red[1][tid][0] + red[2][tid][0] + red[3][tid][0];
    float D1 = red[0][tid][1] + red[1][tid][1] + red[2][tid][1] + red[3][tid][1];
    float N0 = red[0][tid][2] + red[1][tid][2] + red[2][tid][2] + red[3][tid][2];
    float N1 = red[0][tid][3] + red[1][tid][3] + red[2][tid][3] + red[3][tid][3];
    const int wq = cg * WPS + tid;                 // this word in the row
    const float2 xr = *(const float2*)(xf + (size_t)nd * D + 2 * wq);
    float o0 = N0 / (D0 + 1e-16f) + xr.x;
    float o1 = N1 / (D1 + 1e-16f) + xr.y;
    uint32_t ow = (uint32_t)f2b(o0) | ((uint32_t)f2b(o1) << 16);
    abufw[(size_t)nd * Dw + wq] = ow;
    if (nd >= PB0) Apatchw[(size_t)(nd - PB0) * Dw + wq] = ow;
  }
}

// ---------- GEMM1: 256x256 tile, 1024 threads, 16 waves of 64x64 ----------
// 0.5 KB LDS-read/MFMA; 128 KB dynamic LDS; counted vmcnt(4); XOR swizzle;
// XCD-bijective swizzle. C(u16) = bf16(relu(acc*SC + TB)), all rows.
__global__ __launch_bounds__(1024) void k_gemm256(
    const u16* __restrict__ A, const u16* __restrict__ Apatch,
    const u16* __restrict__ BT, u16* __restrict__ C,
    const float* __restrict__ SC, const float* __restrict__ TB,
    int m0g_base, int Mreal, int nby, int Nn, int K) {
  extern __shared__ __align__(16) u16 lds[];  // [A0|A1|B0|B1] x 16384 u16
  const int tid = threadIdx.x;
  const int wave = tid >> 6, lane = tid & 63;

  const int nwg = gridDim.x;
  const int q = nwg >> 3, r = nwg & 7;
  const int xcd = blockIdx.x & 7;
  const int wid = (xcd < r ? xcd * (q + 1) : r * (q + 1) + (xcd - r) * q)
                  + (blockIdx.x >> 3);
  const int bx = wid / nby, by = wid - bx * nby;

  const int m0l = bx * 256;
  const int m0g = m0g_base + m0l;
  const int n0 = by * 256;
  const int wm = (wave >> 2) * 64, wn = (wave & 3) * 64;

  const bool patch = (Apatch != nullptr) && (m0g + 256 > Mreal);
  const u16* Ab = patch ? Apatch : A + (size_t)m0l * K;

  f32x4 acc[4][4] = {};

  const int srow = wave * 8 + (lane >> 3);              // 0..127; srow&7 == lane>>3
  const int scolx = (((lane & 7) ^ (lane >> 3)) * 8);   // pre-swizzled global col
  const int ldst = srow * 64 + (lane & 7) * 8;          // linear LDS dest (elems)
  const u16* ga = Ab + (size_t)srow * K + scolx;
  const u16* gb = BT + (size_t)(n0 + srow) * K + scolx;

#define STAGE(buf, kt)                                                     \
  {                                                                        \
    u16* Ad = lds + (buf) * 16384 + ldst;                                  \
    u16* Bd = lds + 32768 + (buf) * 16384 + ldst;                          \
    gload16(ga + (kt), Ad);                                                \
    gload16(ga + (size_t)128 * K + (kt), Ad + 128 * 64);                   \
    gload16(gb + (kt), Bd);                                                \
    gload16(gb + (size_t)128 * K + (kt), Bd + 128 * 64);                   \
  }

  const int nt = K >> 6;
  STAGE(0, 0);
  int cur = 0;
  for (int t = 0; t < nt; ++t) {
    if (t + 1 < nt) {
      STAGE(cur ^ 1, (size_t)(t + 1) << 6);
      asm volatile("s_waitcnt vmcnt(4)" ::: "memory");
    } else {
      asm volatile("s_waitcnt vmcnt(0)" ::: "memory");
    }
    __builtin_amdgcn_s_barrier();
    __builtin_amdgcn_sched_barrier(0);
    __builtin_amdgcn_s_setprio(1);
    {
      const u16* Ac = lds + cur * 16384;
      const u16* Bc = lds + 32768 + cur * 16384;
#pragma unroll
      for (int s = 0; s < 2; ++s) {
        short8v af[4], bfr[4];
        const int kbx = (s * 32 + (lane >> 4) * 8) ^ ((lane & 7) * 8);
#pragma unroll
        for (int mi = 0; mi < 4; ++mi)
          af[mi] = *(const short8v*)&Ac[(wm + mi * 16 + (lane & 15)) * 64 + kbx];
#pragma unroll
        for (int ni = 0; ni < 4; ++ni)
          bfr[ni] = *(const short8v*)&Bc[(wn + ni * 16 + (lane & 15)) * 64 + kbx];
#pragma unroll
        for (int mi = 0; mi < 4; ++mi)
#pragma unroll
          for (int ni = 0; ni < 4; ++ni)
            acc[mi][ni] = __builtin_amdgcn_mfma_f32_16x16x32_bf16(
                af[mi], bfr[ni], acc[mi][ni], 0, 0, 0);
      }
    }
    __builtin_amdgcn_s_setprio(0);
    __builtin_amdgcn_sched_barrier(0);
    __builtin_amdgcn_s_barrier();
    cur ^= 1;
  }
#undef STAGE

#pragma unroll
  for (int mi = 0; mi < 4; ++mi) {
#pragma unroll
    for (int ni = 0; ni < 4; ++ni) {
      const int cc = n0 + wn + ni * 16 + (lane & 15);
      const int rloc = wm + mi * 16 + (lane >> 4) * 4;
#pragma unroll
      for (int j = 0; j < 4; ++j) {
        float v = fmaxf(acc[mi][ni][j] * SC[cc] + TB[cc], 0.f);
        C[(size_t)(m0l + rloc + j) * Nn + cc] = f2b(v);
      }
    }
  }
}

// ---------- GEMM2: 128x128 bf16 MFMA GEMM, 1024 threads (R12, proven) ----------
// 64KB dbuf -> 2 blocks/CU -> 8 waves/SIMD. Counted vmcnt(2); XOR + XCD swizzle.
// EPI 1: C(f32)[r_glob][c] = acc + B2f[c] + xres[r_glob][c]  (r_glob < Mreal)
template <int EPI>
__global__ __launch_bounds__(1024) void k_gemm(
    const u16* __restrict__ A, const u16* __restrict__ Apatch,
    const u16* __restrict__ BT, void* __restrict__ C,
    const float* __restrict__ SC, const float* __restrict__ TB,
    const float* __restrict__ B2f, const float* __restrict__ xres,
    int m0g_base, int Mreal, int nby, int Nn, int K) {
  __shared__ __align__(16) u16 As[2][128 * 64];
  __shared__ __align__(16) u16 Bs[2][128 * 64];
  const int tid = threadIdx.x;
  const int wave = tid >> 6, lane = tid & 63;

  const int nwg = gridDim.x;
  const int q = nwg >> 3, r = nwg & 7;
  const int xcd = blockIdx.x & 7;
  const int wid = (xcd < r ? xcd * (q + 1) : r * (q + 1) + (xcd - r) * q)
                  + (blockIdx.x >> 3);
  const int bx = wid / nby, by = wid - bx * nby;

  const int m0l = bx * 128;
  const int m0g = m0g_base + m0l;
  const int n0 = by * 128;
  const int wm = (wave >> 2) * 32, wn = (wave & 3) * 32;

  const bool patch = (Apatch != nullptr) && (m0g + 128 > Mreal);
  const u16* Ab = patch ? Apatch : A + (size_t)m0l * K;

  f32x4 acc[2][2] = {};

  const int srow = wave * 8 + (lane >> 3);
  const int scolx = (((lane & 7) ^ (lane >> 3)) * 8);
  const int ldst = srow * 64 + (lane & 7) * 8;
  const u16* ga = Ab + (size_t)srow * K + scolx;
  const u16* gb = BT + (size_t)(n0 + srow) * K + scolx;

#define STAGE(buf, kt)                                                    \
  {                                                                       \
    gload16(ga + (kt), &As[buf][ldst]);                                   \
    gload16(gb + (kt), &Bs[buf][ldst]);                                   \
  }

  const int nt = K >> 6;
  STAGE(0, 0);
  int cur = 0;
  for (int t = 0; t < nt; ++t) {
    if (t + 1 < nt) {
      STAGE(cur ^ 1, (size_t)(t + 1) << 6);
      asm volatile("s_waitcnt vmcnt(2)" ::: "memory");
    } else {
      asm volatile("s_waitcnt vmcnt(0)" ::: "memory");
    }
    __builtin_amdgcn_s_barrier();
    __builtin_amdgcn_sched_barrier(0);
    __builtin_amdgcn_s_setprio(1);
    {
      const u16* Ac = &As[cur][0];
      const u16* Bc = &Bs[cur][0];
#pragma unroll
      for (int s = 0; s < 2; ++s) {
        short8v af[2], bfr[2];
        const int kbx = (s * 32 + (lane >> 4) * 8) ^ ((lane & 7) * 8);
#pragma unroll
        for (int mi = 0; mi < 2; ++mi)
          af[mi] = *(const short8v*)&Ac[(wm + mi * 16 + (lane & 15)) * 64 + kbx];
#pragma unroll
        for (int ni = 0; ni < 2; ++ni)
          bfr[ni] = *(const short8v*)&Bc[(wn + ni * 16 + (lane & 15)) * 64 + kbx];
#pragma unroll
        for (int mi = 0; mi < 2; ++mi)
#pragma unroll
          for (int ni = 0; ni < 2; ++ni)
            acc[mi][ni] = __builtin_amdgcn_mfma_f32_16x16x32_bf16(
                af[mi], bfr[ni], acc[mi][ni], 0, 0, 0);
      }
    }
    __builtin_amdgcn_s_setprio(0);
    __builtin_amdgcn_sched_barrier(0);
    __builtin_amdgcn_s_barrier();
    cur ^= 1;
  }
#undef STAGE

#pragma unroll
  for (int mi = 0; mi < 2; ++mi) {
#pragma unroll
    for (int ni = 0; ni < 2; ++ni) {
      const int cc = n0 + wn + ni * 16 + (lane & 15);
      const int rloc = wm + mi * 16 + (lane >> 4) * 4;
#pragma unroll
      for (int j = 0; j < 4; ++j) {
        float v = acc[mi][ni][j];
        if (EPI == 0) {
          v = fmaxf(v * SC[cc] + TB[cc], 0.f);
          ((u16*)C)[(size_t)(m0l + rloc + j) * Nn + cc] = f2b(v);
        } else {
          const int rg = m0g + rloc + j;
          if (rg < Mreal) {
            v += B2f[cc] + xres[(size_t)rg * Nn + cc];
            ((float*)C)[(size_t)rg * Nn + cc] = v;
          }
        }
      }
    }
  }
}

// ---------------------------------------------------------------------------
extern "C" void kernel_launch(void* const* d_in, const int* in_sizes, int n_in,
                              void* d_out, int out_size, void* d_ws, size_t ws_size,
                              hipStream_t stream) {
  const float* x   = (const float*)d_in[0];
  const int* ei    = (const int*)d_in[1];
  const float* tin = (const float*)d_in[3];
  const float* W1  = (const float*)d_in[4];
  const float* b1  = (const float*)d_in[5];
  const float* gam = (const float*)d_in[6];
  const float* bet = (const float*)d_in[7];
  const float* mea = (const float*)d_in[8];
  const float* var = (const float*)d_in[9];
  const float* W2  = (const float*)d_in[10];
  const float* b2  = (const float*)d_in[11];
  float* dout = (float*)d_out;

  const int n = in_sizes[2];        // 10000 nodes
  const int E = in_sizes[1] / 2;    // 100000 edges
  const int D = in_sizes[11];       // 768
  const int H = in_sizes[5];        // 1536
  const int MPad = ((n + 255) / 256) * 256;  // 10240 (256-aligned)
  const int NBLK = MPad / 256;               // 40 (256-row chunks)
  const int PB0 = MPad - 256;                // first row of the crossing block

  // d_out aliasing plan: abuf = bytes [0,2nD) bf16 agg; xb = [2nD,4nD) bf16 x
  // (dead after k_agg). GEMM2 writes fp32 rows high->low; never clobbers
  // not-yet-consumed abuf rows.
  u16* abuf = (u16*)d_out;
  u16* xb   = (u16*)d_out + (size_t)n * D;

  // workspace layout (256B-aligned slabs)
  uint8_t* w = (uint8_t*)d_ws;
  auto alloc = [&](size_t bytes) {
    uint8_t* p = w; w += (bytes + 255) & ~(size_t)255; return p;
  };
  int*   deg     = (int*)alloc((size_t)n * 4);
  int*   rowptr  = (int*)alloc((size_t)(n + 1) * 4);
  int*   cursor  = (int*)alloc((size_t)n * 4);
  int*   csr_src = (int*)alloc((size_t)E * 4);
  float* SC      = (float*)alloc((size_t)H * 4);
  float* TB      = (float*)alloc((size_t)H * 4);
  float* B2f     = (float*)alloc((size_t)D * 4);
  float* tf      = (float*)alloc(8);                 // t, t*log2e
  u16*   W1T     = (u16*)alloc((size_t)H * D * 2);   // [H][D] bf16
  u16*   W2T     = (u16*)alloc((size_t)D * H * 2);   // [D][H] bf16
  u16*   Apatch  = (u16*)alloc((size_t)256 * D * 2); // last-block A tile (256 rows)
  u16*   hbuf    = (u16*)w;                           // rest of ws

  // how many 256-row blocks of h fit in remaining workspace
  const size_t used = (size_t)(w - (uint8_t*)d_ws);
  const size_t per_blk = (size_t)256 * H * 2;
  size_t avail = (ws_size > used) ? (ws_size - used) : 0;
  int cblk = (int)(avail / per_blk);
  if (cblk < 1) cblk = 1;
  if (cblk > NBLK) cblk = NBLK;

  const int padwords = (MPad - n) * D / 2;  // zero pad rows of Apatch (u32 words)
  const int initN = (n > padwords) ? n : padwords;

  // fused prologue dispatch
  const int nb_init = (initN + 255) / 256;
  const int nb_prep = (H + 255) / 256;
  const int nb_t1 = (H / 32) * (D / 32);
  const int nb_t2 = (D / 32) * (H / 32);
  const int nb_cvt = 1024;
  const int nmisc = nb_init + nb_prep + nb_t1 + nb_t2 + nb_cvt;

  // allow 128 KB dynamic LDS for the 256-tile GEMM (idempotent, capture-safe)
  static bool attr_set = false;
  if (!attr_set) {
    hipFuncSetAttribute((const void*)k_gemm256,
                        hipFuncAttributeMaxDynamicSharedMemorySize, 131072);
    attr_set = true;
  }

  k_misc<<<nmisc, 256, 0, stream>>>(
      deg, (uint32_t*)(Apatch + (size_t)(n - PB0) * D), n, padwords,
      b1, gam, bet, mea, var, b2, tin, SC, TB, B2f, tf, H, D,
      W1, W1T, W2, W2T, x, xb, n * D / 4,
      nb_init, nb_prep, nb_t1, nb_t2, nb_cvt);
  k_hist<<<(E + 255) / 256, 256, 0, stream>>>(ei, deg, E);
  k_scan<<<1, 1024, 0, stream>>>(deg, rowptr, cursor, n, E);
  k_scatter<<<(E + 255) / 256, 256, 0, stream>>>(ei, cursor, csr_src, E);
  k_agg<<<n * 8, 192, 0, stream>>>((const uint32_t*)xb, x, rowptr, csr_src, tf,
                                   (uint32_t*)abuf, (uint32_t*)Apatch, PB0, D);

  // chunks high -> low (see aliasing note above); chunks are 256-row blocks
  int b0 = ((NBLK - 1) / cblk) * cblk;
  for (; b0 >= 0; b0 -= cblk) {
    const int nb = (cblk < NBLK - b0) ? cblk : (NBLK - b0);
    // h[nb*256][H] = bf16(relu(BN(A @ W1))) ; A = abuf rows (+patch last blk)
    k_gemm256<<<nb * (H / 256), 1024, 131072, stream>>>(
        abuf + (size_t)b0 * 256 * D, Apatch, W1T, hbuf,
        SC, TB, b0 * 256, n, H / 256, H, D);
    // dout[rows] = fp32( h @ W2 + b2 + x )  (128-row tiles over the chunk)
    k_gemm<1><<<(nb * 2) * (D / 128), 1024, 0, stream>>>(
        hbuf, nullptr, W2T, dout,
        nullptr, nullptr, B2f, x, b0 * 256, n, D / 128, D, H);
  }
}

// Round 18
// 170.428 us; speedup vs baseline: 1.0463x; 1.0463x over previous
//
#include <hip/hip_runtime.h>
#include <stdint.h>

typedef unsigned short u16;

// ---------- bf16 helpers ----------
__device__ __forceinline__ float b2f(u16 u) {
  union { uint32_t i; float f; } v; v.i = ((uint32_t)u) << 16; return v.f;
}
__device__ __forceinline__ u16 f2b(float f) {
  union { float f; uint32_t i; } v; v.f = f;
  uint32_t x = v.i;
  return (u16)((x + 0x7FFFu + ((x >> 16) & 1u)) >> 16);
}

// async global->LDS, 16B per lane; LDS dst is wave-uniform base + lane*16 (linear)
__device__ __forceinline__ void gload16(const void* g, void* l) {
  __builtin_amdgcn_global_load_lds(
      (const __attribute__((address_space(1))) void*)g,
      (__attribute__((address_space(3))) void*)l, 16, 0, 0);
}

typedef __attribute__((ext_vector_type(8))) short short8v;
typedef __attribute__((ext_vector_type(4))) float f32x4;
typedef __attribute__((ext_vector_type(4))) u16 u16x4;

// ---------- fused prologue: init | prep | transposeW1 | transposeW2 | cvt ----------
__global__ __launch_bounds__(256) void k_misc(
    int* deg, uint32_t* padw, int n, int padwords,
    const float* __restrict__ b1, const float* __restrict__ g,
    const float* __restrict__ be, const float* __restrict__ mu,
    const float* __restrict__ var, const float* __restrict__ b2,
    const float* __restrict__ t, float* SC, float* TB, float* B2f, float* tf,
    int H, int D,
    const float* __restrict__ W1, u16* __restrict__ W1T,
    const float* __restrict__ W2, u16* __restrict__ W2T,
    const float* __restrict__ x, u16* __restrict__ xb, int n4,
    int nb_init, int nb_prep, int nb_t1, int nb_t2, int nb_cvt) {
  __shared__ u16 tile[32][33];
  int b = blockIdx.x;
  const int tid = threadIdx.x;

  if (b < nb_init) {  // zero deg + Apatch pad rows
    int i = b * 256 + tid;
    if (i < n) deg[i] = 0;
    if (i < padwords) padw[i] = 0u;
    return;
  }
  b -= nb_init;
  if (b < nb_prep) {  // BN fold + b2 + temperature (and t*log2e for exp2)
    int i = b * 256 + tid;
    if (i < H) {
      float sc = g[i] * rsqrtf(var[i] + 1e-5f);
      SC[i] = sc;
      TB[i] = (b1[i] - mu[i]) * sc + be[i];
    }
    if (i < D) B2f[i] = b2[i];
    if (i == 0) { tf[0] = t[0]; tf[1] = t[0] * 1.4426950408889634f; }
    return;
  }
  b -= nb_prep;
  if (b < nb_t1) {  // W1 [D][H] -> W1T [H][D] bf16
    const int nbx = H / 32;
    const int bx = (b % nbx) * 32, by = (b / nbx) * 32;
    const int tx = tid & 31, ty = tid >> 5;
    for (int i = 0; i < 32; i += 8)
      tile[ty + i][tx] = f2b(W1[(size_t)(by + ty + i) * H + bx + tx]);
    __syncthreads();
    for (int i = 0; i < 32; i += 8)
      W1T[(size_t)(bx + ty + i) * D + by + tx] = tile[tx][ty + i];
    return;
  }
  b -= nb_t1;
  if (b < nb_t2) {  // W2 [H][D] -> W2T [D][H] bf16
    const int nbx = D / 32;
    const int bx = (b % nbx) * 32, by = (b / nbx) * 32;
    const int tx = tid & 31, ty = tid >> 5;
    for (int i = 0; i < 32; i += 8)
      tile[ty + i][tx] = f2b(W2[(size_t)(by + ty + i) * D + bx + tx]);
    __syncthreads();
    for (int i = 0; i < 32; i += 8)
      W2T[(size_t)(bx + ty + i) * H + by + tx] = tile[tx][ty + i];
    return;
  }
  b -= nb_t2;
  {  // x fp32 -> xb bf16, grid-stride, float4/ushort4
    int i = b * 256 + tid;
    const int stride = nb_cvt * 256;
    for (; i < n4; i += stride) {
      f32x4 v = *(const f32x4*)(x + (size_t)i * 4);
      u16x4 o;
      o[0] = f2b(v[0]); o[1] = f2b(v[1]); o[2] = f2b(v[2]); o[3] = f2b(v[3]);
      *(u16x4*)(xb + (size_t)i * 4) = o;
    }
  }
}

// ---------- CSR build ----------
__global__ void k_hist(const int* __restrict__ ei, int* deg, int E) {
  int e = blockIdx.x * 256 + threadIdx.x;
  if (e < E) atomicAdd(&deg[ei[E + e]], 1);  // dst = ei[1][e]
}

// shuffle-based scan: 2 barriers instead of 20
__global__ void k_scan(const int* __restrict__ deg, int* rowptr, int* cursor, int n, int E) {
  __shared__ int wsum[16];
  const int tid = threadIdx.x;
  const int lane = tid & 63, wv = tid >> 6;
  const int CH = (n + 1023) / 1024;
  const int base = tid * CH;
  int s = 0;
  for (int i = 0; i < CH; ++i) {
    int idx = base + i;
    s += (idx < n) ? deg[idx] : 0;
  }
  int incl = s;
  for (int d2 = 1; d2 < 64; d2 <<= 1) {
    int t2 = __shfl_up(incl, d2);
    if (lane >= d2) incl += t2;
  }
  if (lane == 63) wsum[wv] = incl;
  __syncthreads();
  if (wv == 0) {
    int v = (lane < 16) ? wsum[lane] : 0;
    for (int d2 = 1; d2 < 16; d2 <<= 1) {
      int t2 = __shfl_up(v, d2);
      if (lane >= d2) v += t2;
    }
    if (lane < 16) wsum[lane] = v;
  }
  __syncthreads();
  int run = (wv ? wsum[wv - 1] : 0) + (incl - s);
  for (int i = 0; i < CH; ++i) {
    int idx = base + i;
    if (idx < n) {
      rowptr[idx] = run; cursor[idx] = run;
      run += deg[idx];
    }
  }
  if (tid == 1023) rowptr[n] = run;  // == E
}

__global__ void k_scatter(const int* __restrict__ ei, int* cursor, int* csr_src, int E) {
  int e = blockIdx.x * 256 + threadIdx.x;
  if (e < E) {
    int d = ei[E + e];
    int p = atomicAdd(&cursor[d], 1);
    csr_src[p] = ei[e];  // store src node id
  }
}

// ---------- XCD-sliced, node-batched gather + segment-softmax + aggregate ----------
// grid = n blocks = (n/8 node-groups) x 8 slices; cg = blockIdx & 7 binds a
// 96-channel slice to one XCD (HW round-robin). Per-XCD gather working set =
// n x 192 B = 1.92 MB -> L2-resident: gathers become L2 hits (FETCH 146->~40MB,
// verified in R17). R17's mistake (80k tiny blocks, 4B loads) fixed by:
// 8 nodes per block (overhead amortized, block count back to n) and
// uint2 (8 B) gather loads (8 edge-groups x 24 words).
__global__ __launch_bounds__(192) void k_agg(const uint32_t* __restrict__ xw,
    const float* __restrict__ xf,
    const int* __restrict__ rowptr, const int* __restrict__ csr_src,
    const float* __restrict__ tf, uint32_t* __restrict__ abufw,
    uint32_t* __restrict__ Apatchw, int PB0, int D) {
  __shared__ float red[8][24][8];   // [edge-group][word-pair][d0..d3,m0..m3]
  __shared__ float red2[24][8];
  const int bid = blockIdx.x;
  const int cg = bid & 7;           // slice -> XCD
  const int ng = bid >> 3;          // node-group (8 nodes)
  const int tid = threadIdx.x;
  const int eg = tid / 24;          // edge-group 0..7
  const int wt = tid - eg * 24;     // uint2 index within slice 0..23
  const float tl = tf[1];           // t * log2(e)
  const int Dw = D >> 1;            // 384 words per row
  const int wo = cg * 48 + wt * 2;  // this thread's first word in the row

  for (int nl = 0; nl < 8; ++nl) {
    const int nd = ng * 8 + nl;
    const int beg = rowptr[nd], end = rowptr[nd + 1];
    float d0 = 0.f, d1 = 0.f, d2 = 0.f, d3 = 0.f;
    float m0 = 0.f, m1 = 0.f, m2 = 0.f, m3 = 0.f;
    for (int j = beg + eg; j < end; j += 8) {
      const uint2 v = *(const uint2*)(xw + (size_t)csr_src[j] * Dw + wo);
      float lo0 = __uint_as_float(v.x << 16);
      float hi0 = __uint_as_float(v.x & 0xFFFF0000u);
      float lo1 = __uint_as_float(v.y << 16);
      float hi1 = __uint_as_float(v.y & 0xFFFF0000u);
      float g0 = fmaxf(lo0, 0.f) + 1e-7f;
      float g1 = fmaxf(hi0, 0.f) + 1e-7f;
      float g2 = fmaxf(lo1, 0.f) + 1e-7f;
      float g3 = fmaxf(hi1, 0.f) + 1e-7f;
      float e0 = __builtin_amdgcn_exp2f(g0 * tl);
      float e1 = __builtin_amdgcn_exp2f(g1 * tl);
      float e2 = __builtin_amdgcn_exp2f(g2 * tl);
      float e3 = __builtin_amdgcn_exp2f(g3 * tl);
      d0 += e0; m0 = fmaf(g0, e0, m0);
      d1 += e1; m1 = fmaf(g1, e1, m1);
      d2 += e2; m2 = fmaf(g2, e2, m2);
      d3 += e3; m3 = fmaf(g3, e3, m3);
    }
    red[eg][wt][0] = d0; red[eg][wt][1] = d1;
    red[eg][wt][2] = d2; red[eg][wt][3] = d3;
    red[eg][wt][4] = m0; red[eg][wt][5] = m1;
    red[eg][wt][6] = m2; red[eg][wt][7] = m3;
    __syncthreads();
    {  // step 1: 192 threads each sum one (word, slot) over 8 groups
      const int w = tid >> 3, sv = tid & 7;
      float s = red[0][w][sv] + red[1][w][sv] + red[2][w][sv] + red[3][w][sv]
              + red[4][w][sv] + red[5][w][sv] + red[6][w][sv] + red[7][w][sv];
      red2[w][sv] = s;
    }
    __syncthreads();
    if (tid < 24) {  // step 2: finalize 4 channels, pack, store
      const int wq = cg * 48 + tid * 2;
      float D0 = red2[tid][0], D1 = red2[tid][1];
      float D2 = red2[tid][2], D3 = red2[tid][3];
      float N0 = red2[tid][4], N1 = red2[tid][5];
      float N2 = red2[tid][6], N3 = red2[tid][7];
      const f32x4 xr = *(const f32x4*)(xf + (size_t)nd * D + 2 * wq);
      float o0 = N0 / (D0 + 1e-16f) + xr[0];
      float o1 = N1 / (D1 + 1e-16f) + xr[1];
      float o2 = N2 / (D2 + 1e-16f) + xr[2];
      float o3 = N3 / (D3 + 1e-16f) + xr[3];
      uint2 ow;
      ow.x = (uint32_t)f2b(o0) | ((uint32_t)f2b(o1) << 16);
      ow.y = (uint32_t)f2b(o2) | ((uint32_t)f2b(o3) << 16);
      *(uint2*)(abufw + (size_t)nd * Dw + wq) = ow;
      if (nd >= PB0) *(uint2*)(Apatchw + (size_t)(nd - PB0) * Dw + wq) = ow;
    }
    __syncthreads();
  }
}

// ---------- GEMM1: 256x256 tile, 1024 threads, 16 waves of 64x64 ----------
// 0.5 KB LDS-read/MFMA; 128 KB dynamic LDS; counted vmcnt(4); XOR swizzle;
// XCD-bijective swizzle. C(u16) = bf16(relu(acc*SC + TB)), all rows.
__global__ __launch_bounds__(1024) void k_gemm256(
    const u16* __restrict__ A, const u16* __restrict__ Apatch,
    const u16* __restrict__ BT, u16* __restrict__ C,
    const float* __restrict__ SC, const float* __restrict__ TB,
    int m0g_base, int Mreal, int nby, int Nn, int K) {
  extern __shared__ __align__(16) u16 lds[];  // [A0|A1|B0|B1] x 16384 u16
  const int tid = threadIdx.x;
  const int wave = tid >> 6, lane = tid & 63;

  const int nwg = gridDim.x;
  const int q = nwg >> 3, r = nwg & 7;
  const int xcd = blockIdx.x & 7;
  const int wid = (xcd < r ? xcd * (q + 1) : r * (q + 1) + (xcd - r) * q)
                  + (blockIdx.x >> 3);
  const int bx = wid / nby, by = wid - bx * nby;

  const int m0l = bx * 256;
  const int m0g = m0g_base + m0l;
  const int n0 = by * 256;
  const int wm = (wave >> 2) * 64, wn = (wave & 3) * 64;

  const bool patch = (Apatch != nullptr) && (m0g + 256 > Mreal);
  const u16* Ab = patch ? Apatch : A + (size_t)m0l * K;

  f32x4 acc[4][4] = {};

  const int srow = wave * 8 + (lane >> 3);              // 0..127; srow&7 == lane>>3
  const int scolx = (((lane & 7) ^ (lane >> 3)) * 8);   // pre-swizzled global col
  const int ldst = srow * 64 + (lane & 7) * 8;          // linear LDS dest (elems)
  const u16* ga = Ab + (size_t)srow * K + scolx;
  const u16* gb = BT + (size_t)(n0 + srow) * K + scolx;

#define STAGE(buf, kt)                                                     \
  {                                                                        \
    u16* Ad = lds + (buf) * 16384 + ldst;                                  \
    u16* Bd = lds + 32768 + (buf) * 16384 + ldst;                          \
    gload16(ga + (kt), Ad);                                                \
    gload16(ga + (size_t)128 * K + (kt), Ad + 128 * 64);                   \
    gload16(gb + (kt), Bd);                                                \
    gload16(gb + (size_t)128 * K + (kt), Bd + 128 * 64);                   \
  }

  const int nt = K >> 6;
  STAGE(0, 0);
  int cur = 0;
  for (int t = 0; t < nt; ++t) {
    if (t + 1 < nt) {
      STAGE(cur ^ 1, (size_t)(t + 1) << 6);
      asm volatile("s_waitcnt vmcnt(4)" ::: "memory");
    } else {
      asm volatile("s_waitcnt vmcnt(0)" ::: "memory");
    }
    __builtin_amdgcn_s_barrier();
    __builtin_amdgcn_sched_barrier(0);
    __builtin_amdgcn_s_setprio(1);
    {
      const u16* Ac = lds + cur * 16384;
      const u16* Bc = lds + 32768 + cur * 16384;
#pragma unroll
      for (int s = 0; s < 2; ++s) {
        short8v af[4], bfr[4];
        const int kbx = (s * 32 + (lane >> 4) * 8) ^ ((lane & 7) * 8);
#pragma unroll
        for (int mi = 0; mi < 4; ++mi)
          af[mi] = *(const short8v*)&Ac[(wm + mi * 16 + (lane & 15)) * 64 + kbx];
#pragma unroll
        for (int ni = 0; ni < 4; ++ni)
          bfr[ni] = *(const short8v*)&Bc[(wn + ni * 16 + (lane & 15)) * 64 + kbx];
#pragma unroll
        for (int mi = 0; mi < 4; ++mi)
#pragma unroll
          for (int ni = 0; ni < 4; ++ni)
            acc[mi][ni] = __builtin_amdgcn_mfma_f32_16x16x32_bf16(
                af[mi], bfr[ni], acc[mi][ni], 0, 0, 0);
      }
    }
    __builtin_amdgcn_s_setprio(0);
    __builtin_amdgcn_sched_barrier(0);
    __builtin_amdgcn_s_barrier();
    cur ^= 1;
  }
#undef STAGE

#pragma unroll
  for (int mi = 0; mi < 4; ++mi) {
#pragma unroll
    for (int ni = 0; ni < 4; ++ni) {
      const int cc = n0 + wn + ni * 16 + (lane & 15);
      const int rloc = wm + mi * 16 + (lane >> 4) * 4;
#pragma unroll
      for (int j = 0; j < 4; ++j) {
        float v = fmaxf(acc[mi][ni][j] * SC[cc] + TB[cc], 0.f);
        C[(size_t)(m0l + rloc + j) * Nn + cc] = f2b(v);
      }
    }
  }
}

// ---------- GEMM2: 128x128 bf16 MFMA GEMM, 1024 threads (R12, proven) ----------
// 64KB dbuf -> 2 blocks/CU -> 8 waves/SIMD. Counted vmcnt(2); XOR + XCD swizzle.
// EPI 1: C(f32)[r_glob][c] = acc + B2f[c] + xres[r_glob][c]  (r_glob < Mreal)
template <int EPI>
__global__ __launch_bounds__(1024) void k_gemm(
    const u16* __restrict__ A, const u16* __restrict__ Apatch,
    const u16* __restrict__ BT, void* __restrict__ C,
    const float* __restrict__ SC, const float* __restrict__ TB,
    const float* __restrict__ B2f, const float* __restrict__ xres,
    int m0g_base, int Mreal, int nby, int Nn, int K) {
  __shared__ __align__(16) u16 As[2][128 * 64];
  __shared__ __align__(16) u16 Bs[2][128 * 64];
  const int tid = threadIdx.x;
  const int wave = tid >> 6, lane = tid & 63;

  const int nwg = gridDim.x;
  const int q = nwg >> 3, r = nwg & 7;
  const int xcd = blockIdx.x & 7;
  const int wid = (xcd < r ? xcd * (q + 1) : r * (q + 1) + (xcd - r) * q)
                  + (blockIdx.x >> 3);
  const int bx = wid / nby, by = wid - bx * nby;

  const int m0l = bx * 128;
  const int m0g = m0g_base + m0l;
  const int n0 = by * 128;
  const int wm = (wave >> 2) * 32, wn = (wave & 3) * 32;

  const bool patch = (Apatch != nullptr) && (m0g + 128 > Mreal);
  const u16* Ab = patch ? Apatch : A + (size_t)m0l * K;

  f32x4 acc[2][2] = {};

  const int srow = wave * 8 + (lane >> 3);
  const int scolx = (((lane & 7) ^ (lane >> 3)) * 8);
  const int ldst = srow * 64 + (lane & 7) * 8;
  const u16* ga = Ab + (size_t)srow * K + scolx;
  const u16* gb = BT + (size_t)(n0 + srow) * K + scolx;

#define STAGE(buf, kt)                                                    \
  {                                                                       \
    gload16(ga + (kt), &As[buf][ldst]);                                   \
    gload16(gb + (kt), &Bs[buf][ldst]);                                   \
  }

  const int nt = K >> 6;
  STAGE(0, 0);
  int cur = 0;
  for (int t = 0; t < nt; ++t) {
    if (t + 1 < nt) {
      STAGE(cur ^ 1, (size_t)(t + 1) << 6);
      asm volatile("s_waitcnt vmcnt(2)" ::: "memory");
    } else {
      asm volatile("s_waitcnt vmcnt(0)" ::: "memory");
    }
    __builtin_amdgcn_s_barrier();
    __builtin_amdgcn_sched_barrier(0);
    __builtin_amdgcn_s_setprio(1);
    {
      const u16* Ac = &As[cur][0];
      const u16* Bc = &Bs[cur][0];
#pragma unroll
      for (int s = 0; s < 2; ++s) {
        short8v af[2], bfr[2];
        const int kbx = (s * 32 + (lane >> 4) * 8) ^ ((lane & 7) * 8);
#pragma unroll
        for (int mi = 0; mi < 2; ++mi)
          af[mi] = *(const short8v*)&Ac[(wm + mi * 16 + (lane & 15)) * 64 + kbx];
#pragma unroll
        for (int ni = 0; ni < 2; ++ni)
          bfr[ni] = *(const short8v*)&Bc[(wn + ni * 16 + (lane & 15)) * 64 + kbx];
#pragma unroll
        for (int mi = 0; mi < 2; ++mi)
#pragma unroll
          for (int ni = 0; ni < 2; ++ni)
            acc[mi][ni] = __builtin_amdgcn_mfma_f32_16x16x32_bf16(
                af[mi], bfr[ni], acc[mi][ni], 0, 0, 0);
      }
    }
    __builtin_amdgcn_s_setprio(0);
    __builtin_amdgcn_sched_barrier(0);
    __builtin_amdgcn_s_barrier();
    cur ^= 1;
  }
#undef STAGE

#pragma unroll
  for (int mi = 0; mi < 2; ++mi) {
#pragma unroll
    for (int ni = 0; ni < 2; ++ni) {
      const int cc = n0 + wn + ni * 16 + (lane & 15);
      const int rloc = wm + mi * 16 + (lane >> 4) * 4;
#pragma unroll
      for (int j = 0; j < 4; ++j) {
        float v = acc[mi][ni][j];
        if (EPI == 0) {
          v = fmaxf(v * SC[cc] + TB[cc], 0.f);
          ((u16*)C)[(size_t)(m0l + rloc + j) * Nn + cc] = f2b(v);
        } else {
          const int rg = m0g + rloc + j;
          if (rg < Mreal) {
            v += B2f[cc] + xres[(size_t)rg * Nn + cc];
            ((float*)C)[(size_t)rg * Nn + cc] = v;
          }
        }
      }
    }
  }
}

// ---------------------------------------------------------------------------
extern "C" void kernel_launch(void* const* d_in, const int* in_sizes, int n_in,
                              void* d_out, int out_size, void* d_ws, size_t ws_size,
                              hipStream_t stream) {
  const float* x   = (const float*)d_in[0];
  const int* ei    = (const int*)d_in[1];
  const float* tin = (const float*)d_in[3];
  const float* W1  = (const float*)d_in[4];
  const float* b1  = (const float*)d_in[5];
  const float* gam = (const float*)d_in[6];
  const float* bet = (const float*)d_in[7];
  const float* mea = (const float*)d_in[8];
  const float* var = (const float*)d_in[9];
  const float* W2  = (const float*)d_in[10];
  const float* b2  = (const float*)d_in[11];
  float* dout = (float*)d_out;

  const int n = in_sizes[2];        // 10000 nodes
  const int E = in_sizes[1] / 2;    // 100000 edges
  const int D = in_sizes[11];       // 768
  const int H = in_sizes[5];        // 1536
  const int MPad = ((n + 255) / 256) * 256;  // 10240 (256-aligned)
  const int NBLK = MPad / 256;               // 40 (256-row chunks)
  const int PB0 = MPad - 256;                // first row of the crossing block

  // d_out aliasing plan: abuf = bytes [0,2nD) bf16 agg; xb = [2nD,4nD) bf16 x
  // (dead after k_agg). GEMM2 writes fp32 rows high->low; never clobbers
  // not-yet-consumed abuf rows.
  u16* abuf = (u16*)d_out;
  u16* xb   = (u16*)d_out + (size_t)n * D;

  // workspace layout (256B-aligned slabs)
  uint8_t* w = (uint8_t*)d_ws;
  auto alloc = [&](size_t bytes) {
    uint8_t* p = w; w += (bytes + 255) & ~(size_t)255; return p;
  };
  int*   deg     = (int*)alloc((size_t)n * 4);
  int*   rowptr  = (int*)alloc((size_t)(n + 1) * 4);
  int*   cursor  = (int*)alloc((size_t)n * 4);
  int*   csr_src = (int*)alloc((size_t)E * 4);
  float* SC      = (float*)alloc((size_t)H * 4);
  float* TB      = (float*)alloc((size_t)H * 4);
  float* B2f     = (float*)alloc((size_t)D * 4);
  float* tf      = (float*)alloc(8);                 // t, t*log2e
  u16*   W1T     = (u16*)alloc((size_t)H * D * 2);   // [H][D] bf16
  u16*   W2T     = (u16*)alloc((size_t)D * H * 2);   // [D][H] bf16
  u16*   Apatch  = (u16*)alloc((size_t)256 * D * 2); // last-block A tile (256 rows)
  u16*   hbuf    = (u16*)w;                           // rest of ws

  // how many 256-row blocks of h fit in remaining workspace
  const size_t used = (size_t)(w - (uint8_t*)d_ws);
  const size_t per_blk = (size_t)256 * H * 2;
  size_t avail = (ws_size > used) ? (ws_size - used) : 0;
  int cblk = (int)(avail / per_blk);
  if (cblk < 1) cblk = 1;
  if (cblk > NBLK) cblk = NBLK;

  const int padwords = (MPad - n) * D / 2;  // zero pad rows of Apatch (u32 words)
  const int initN = (n > padwords) ? n : padwords;

  // fused prologue dispatch
  const int nb_init = (initN + 255) / 256;
  const int nb_prep = (H + 255) / 256;
  const int nb_t1 = (H / 32) * (D / 32);
  const int nb_t2 = (D / 32) * (H / 32);
  const int nb_cvt = 1024;
  const int nmisc = nb_init + nb_prep + nb_t1 + nb_t2 + nb_cvt;

  // allow 128 KB dynamic LDS for the 256-tile GEMM (idempotent, capture-safe)
  static bool attr_set = false;
  if (!attr_set) {
    hipFuncSetAttribute((const void*)k_gemm256,
                        hipFuncAttributeMaxDynamicSharedMemorySize, 131072);
    attr_set = true;
  }

  k_misc<<<nmisc, 256, 0, stream>>>(
      deg, (uint32_t*)(Apatch + (size_t)(n - PB0) * D), n, padwords,
      b1, gam, bet, mea, var, b2, tin, SC, TB, B2f, tf, H, D,
      W1, W1T, W2, W2T, x, xb, n * D / 4,
      nb_init, nb_prep, nb_t1, nb_t2, nb_cvt);
  k_hist<<<(E + 255) / 256, 256, 0, stream>>>(ei, deg, E);
  k_scan<<<1, 1024, 0, stream>>>(deg, rowptr, cursor, n, E);
  k_scatter<<<(E + 255) / 256, 256, 0, stream>>>(ei, cursor, csr_src, E);
  k_agg<<<n, 192, 0, stream>>>((const uint32_t*)xb, x, rowptr, csr_src, tf,
                               (uint32_t*)abuf, (uint32_t*)Apatch, PB0, D);

  // chunks high -> low (see aliasing note above); chunks are 256-row blocks
  int b0 = ((NBLK - 1) / cblk) * cblk;
  for (; b0 >= 0; b0 -= cblk) {
    const int nb = (cblk < NBLK - b0) ? cblk : (NBLK - b0);
    // h[nb*256][H] = bf16(relu(BN(A @ W1))) ; A = abuf rows (+patch last blk)
    k_gemm256<<<nb * (H / 256), 1024, 131072, stream>>>(
        abuf + (size_t)b0 * 256 * D, Apatch, W1T, hbuf,
        SC, TB, b0 * 256, n, H / 256, H, D);
    // dout[rows] = fp32( h @ W2 + b2 + x )  (128-row tiles over the chunk)
    k_gemm<1><<<(nb * 2) * (D / 128), 1024, 0, stream>>>(
        hbuf, nullptr, W2T, dout,
        nullptr, nullptr, B2f, x, b0 * 256, n, D / 128, D, H);
  }
}

// Round 19
// 136.143 us; speedup vs baseline: 1.3098x; 1.2518x over previous
//
#include <hip/hip_runtime.h>
#include <stdint.h>

typedef unsigned short u16;

// ---------- bf16 helpers ----------
__device__ __forceinline__ float b2f(u16 u) {
  union { uint32_t i; float f; } v; v.i = ((uint32_t)u) << 16; return v.f;
}
__device__ __forceinline__ u16 f2b(float f) {
  union { float f; uint32_t i; } v; v.f = f;
  uint32_t x = v.i;
  return (u16)((x + 0x7FFFu + ((x >> 16) & 1u)) >> 16);
}

// async global->LDS, 16B per lane; LDS dst is wave-uniform base + lane*16 (linear)
__device__ __forceinline__ void gload16(const void* g, void* l) {
  __builtin_amdgcn_global_load_lds(
      (const __attribute__((address_space(1))) void*)g,
      (__attribute__((address_space(3))) void*)l, 16, 0, 0);
}

typedef __attribute__((ext_vector_type(8))) short short8v;
typedef __attribute__((ext_vector_type(4))) float f32x4;
typedef __attribute__((ext_vector_type(4))) u16 u16x4;

// ---------- fused prologue: init | prep | transposeW1 | transposeW2 | cvt ----------
__global__ __launch_bounds__(256) void k_misc(
    int* deg, uint32_t* padw, int n, int padwords,
    const float* __restrict__ b1, const float* __restrict__ g,
    const float* __restrict__ be, const float* __restrict__ mu,
    const float* __restrict__ var, const float* __restrict__ b2,
    const float* __restrict__ t, float* SC, float* TB, float* B2f, float* tf,
    int H, int D,
    const float* __restrict__ W1, u16* __restrict__ W1T,
    const float* __restrict__ W2, u16* __restrict__ W2T,
    const float* __restrict__ x, u16* __restrict__ xb, int n4,
    int nb_init, int nb_prep, int nb_t1, int nb_t2, int nb_cvt) {
  __shared__ u16 tile[32][33];
  int b = blockIdx.x;
  const int tid = threadIdx.x;

  if (b < nb_init) {  // zero deg + Apatch pad rows
    int i = b * 256 + tid;
    if (i < n) deg[i] = 0;
    if (i < padwords) padw[i] = 0u;
    return;
  }
  b -= nb_init;
  if (b < nb_prep) {  // BN fold + b2 + temperature (and t*log2e for exp2)
    int i = b * 256 + tid;
    if (i < H) {
      float sc = g[i] * rsqrtf(var[i] + 1e-5f);
      SC[i] = sc;
      TB[i] = (b1[i] - mu[i]) * sc + be[i];
    }
    if (i < D) B2f[i] = b2[i];
    if (i == 0) { tf[0] = t[0]; tf[1] = t[0] * 1.4426950408889634f; }
    return;
  }
  b -= nb_prep;
  if (b < nb_t1) {  // W1 [D][H] -> W1T [H][D] bf16
    const int nbx = H / 32;
    const int bx = (b % nbx) * 32, by = (b / nbx) * 32;
    const int tx = tid & 31, ty = tid >> 5;
    for (int i = 0; i < 32; i += 8)
      tile[ty + i][tx] = f2b(W1[(size_t)(by + ty + i) * H + bx + tx]);
    __syncthreads();
    for (int i = 0; i < 32; i += 8)
      W1T[(size_t)(bx + ty + i) * D + by + tx] = tile[tx][ty + i];
    return;
  }
  b -= nb_t1;
  if (b < nb_t2) {  // W2 [H][D] -> W2T [D][H] bf16
    const int nbx = D / 32;
    const int bx = (b % nbx) * 32, by = (b / nbx) * 32;
    const int tx = tid & 31, ty = tid >> 5;
    for (int i = 0; i < 32; i += 8)
      tile[ty + i][tx] = f2b(W2[(size_t)(by + ty + i) * D + bx + tx]);
    __syncthreads();
    for (int i = 0; i < 32; i += 8)
      W2T[(size_t)(bx + ty + i) * H + by + tx] = tile[tx][ty + i];
    return;
  }
  b -= nb_t2;
  {  // x fp32 -> xb bf16, grid-stride, float4/ushort4
    int i = b * 256 + tid;
    const int stride = nb_cvt * 256;
    for (; i < n4; i += stride) {
      f32x4 v = *(const f32x4*)(x + (size_t)i * 4);
      u16x4 o;
      o[0] = f2b(v[0]); o[1] = f2b(v[1]); o[2] = f2b(v[2]); o[3] = f2b(v[3]);
      *(u16x4*)(xb + (size_t)i * 4) = o;
    }
  }
}

// ---------- CSR build ----------
__global__ void k_hist(const int* __restrict__ ei, int* deg, int E) {
  int e = blockIdx.x * 256 + threadIdx.x;
  if (e < E) atomicAdd(&deg[ei[E + e]], 1);  // dst = ei[1][e]
}

// shuffle-based scan: 2 barriers instead of 20
__global__ void k_scan(const int* __restrict__ deg, int* rowptr, int* cursor, int n, int E) {
  __shared__ int wsum[16];
  const int tid = threadIdx.x;
  const int lane = tid & 63, wv = tid >> 6;
  const int CH = (n + 1023) / 1024;
  const int base = tid * CH;
  int s = 0;
  for (int i = 0; i < CH; ++i) {
    int idx = base + i;
    s += (idx < n) ? deg[idx] : 0;
  }
  int incl = s;
  for (int d2 = 1; d2 < 64; d2 <<= 1) {
    int t2 = __shfl_up(incl, d2);
    if (lane >= d2) incl += t2;
  }
  if (lane == 63) wsum[wv] = incl;
  __syncthreads();
  if (wv == 0) {
    int v = (lane < 16) ? wsum[lane] : 0;
    for (int d2 = 1; d2 < 16; d2 <<= 1) {
      int t2 = __shfl_up(v, d2);
      if (lane >= d2) v += t2;
    }
    if (lane < 16) wsum[lane] = v;
  }
  __syncthreads();
  int run = (wv ? wsum[wv - 1] : 0) + (incl - s);
  for (int i = 0; i < CH; ++i) {
    int idx = base + i;
    if (idx < n) {
      rowptr[idx] = run; cursor[idx] = run;
      run += deg[idx];
    }
  }
  if (tid == 1023) rowptr[n] = run;  // == E
}

__global__ void k_scatter(const int* __restrict__ ei, int* cursor, int* csr_src, int E) {
  int e = blockIdx.x * 256 + threadIdx.x;
  if (e < E) {
    int d = ei[E + e];
    int p = atomicAdd(&cursor[d], 1);
    csr_src[p] = ei[e];  // store src node id
  }
}

// ---------- fused gather + segment-softmax + aggregate + root add (R14 form) ----------
// one block per node, 192 threads, 4 channels (2 bf16-pair words) per thread.
// No max-subtraction (logits bounded, softmax shift-invariant -> identical).
// exp via exp2 with host-folded t*log2e. 8-way edge unroll.
// Measured floor: ~34 us = 146 MB compulsory 8-XCD-replicated gather traffic;
// de-replication via channel-slicing costs more than it saves (R17/R18).
__global__ __launch_bounds__(192) void k_agg(const uint32_t* __restrict__ xw,
    const float* __restrict__ xf,
    const int* __restrict__ rowptr, const int* __restrict__ csr_src,
    const float* __restrict__ tf, u16* __restrict__ abuf,
    u16* __restrict__ Apatch, int PB0, int D) {
  const int nd = blockIdx.x;
  const int tid = threadIdx.x;
  const float tl = tf[1];  // t * log2(e)
  const int beg = rowptr[nd], end = rowptr[nd + 1];
  const int Dw = D >> 1;      // words per row
  const int wo = tid * 2;     // this thread's word offset (4 channels)
  float den[4] = {0.f, 0.f, 0.f, 0.f};
  float num[4] = {0.f, 0.f, 0.f, 0.f};

#define PROC(vv)                                                       \
  {                                                                    \
    _Pragma("unroll") for (int h = 0; h < 2; ++h) {                    \
      uint32_t u = h ? (vv).y : (vv).x;                                \
      float lo = __uint_as_float(u << 16);                             \
      float hi = __uint_as_float(u & 0xFFFF0000u);                     \
      float g0 = fmaxf(lo, 0.f) + 1e-7f;                               \
      float g1 = fmaxf(hi, 0.f) + 1e-7f;                               \
      float e0 = __builtin_amdgcn_exp2f(g0 * tl);                      \
      float e1 = __builtin_amdgcn_exp2f(g1 * tl);                      \
      den[2 * h] += e0;     num[2 * h] = fmaf(g0, e0, num[2 * h]);     \
      den[2 * h + 1] += e1; num[2 * h + 1] = fmaf(g1, e1, num[2 * h + 1]); \
    }                                                                  \
  }

  int j = beg;
  for (; j + 8 <= end; j += 8) {
    uint2 v[8];
#pragma unroll
    for (int k = 0; k < 8; ++k)
      v[k] = *(const uint2*)(xw + (size_t)csr_src[j + k] * Dw + wo);
#pragma unroll
    for (int k = 0; k < 8; ++k) PROC(v[k]);
  }
  for (; j + 4 <= end; j += 4) {
    uint2 v[4];
#pragma unroll
    for (int k = 0; k < 4; ++k)
      v[k] = *(const uint2*)(xw + (size_t)csr_src[j + k] * Dw + wo);
#pragma unroll
    for (int k = 0; k < 4; ++k) PROC(v[k]);
  }
  for (; j < end; ++j) {
    const uint2 v = *(const uint2*)(xw + (size_t)csr_src[j] * Dw + wo);
    PROC(v);
  }
#undef PROC

  const size_t ro = (size_t)nd * D + tid * 4;
  const f32x4 xr = *(const f32x4*)(xf + ro);
  u16x4 o;
#pragma unroll
  for (int c = 0; c < 4; ++c)
    o[c] = f2b(num[c] / (den[c] + 1e-16f) + xr[c]);
  *(u16x4*)(abuf + ro) = o;
  if (nd >= PB0) *(u16x4*)(Apatch + (size_t)(nd - PB0) * D + tid * 4) = o;
}

// ---------- GEMM1: 256x256 tile, 1024 threads, 16 waves of 64x64 ----------
// 0.5 KB LDS-read/MFMA; 128 KB dynamic LDS; counted vmcnt(4); XOR swizzle;
// XCD-bijective swizzle. C(u16) = bf16(relu(acc*SC + TB)), all rows.
__global__ __launch_bounds__(1024) void k_gemm256(
    const u16* __restrict__ A, const u16* __restrict__ Apatch,
    const u16* __restrict__ BT, u16* __restrict__ C,
    const float* __restrict__ SC, const float* __restrict__ TB,
    int m0g_base, int Mreal, int nby, int Nn, int K) {
  extern __shared__ __align__(16) u16 lds[];  // [A0|A1|B0|B1] x 16384 u16
  const int tid = threadIdx.x;
  const int wave = tid >> 6, lane = tid & 63;

  const int nwg = gridDim.x;
  const int q = nwg >> 3, r = nwg & 7;
  const int xcd = blockIdx.x & 7;
  const int wid = (xcd < r ? xcd * (q + 1) : r * (q + 1) + (xcd - r) * q)
                  + (blockIdx.x >> 3);
  const int bx = wid / nby, by = wid - bx * nby;

  const int m0l = bx * 256;
  const int m0g = m0g_base + m0l;
  const int n0 = by * 256;
  const int wm = (wave >> 2) * 64, wn = (wave & 3) * 64;

  const bool patch = (Apatch != nullptr) && (m0g + 256 > Mreal);
  const u16* Ab = patch ? Apatch : A + (size_t)m0l * K;

  f32x4 acc[4][4] = {};

  const int srow = wave * 8 + (lane >> 3);              // 0..127; srow&7 == lane>>3
  const int scolx = (((lane & 7) ^ (lane >> 3)) * 8);   // pre-swizzled global col
  const int ldst = srow * 64 + (lane & 7) * 8;          // linear LDS dest (elems)
  const u16* ga = Ab + (size_t)srow * K + scolx;
  const u16* gb = BT + (size_t)(n0 + srow) * K + scolx;

#define STAGE(buf, kt)                                                     \
  {                                                                        \
    u16* Ad = lds + (buf) * 16384 + ldst;                                  \
    u16* Bd = lds + 32768 + (buf) * 16384 + ldst;                          \
    gload16(ga + (kt), Ad);                                                \
    gload16(ga + (size_t)128 * K + (kt), Ad + 128 * 64);                   \
    gload16(gb + (kt), Bd);                                                \
    gload16(gb + (size_t)128 * K + (kt), Bd + 128 * 64);                   \
  }

  const int nt = K >> 6;
  STAGE(0, 0);
  int cur = 0;
  for (int t = 0; t < nt; ++t) {
    if (t + 1 < nt) {
      STAGE(cur ^ 1, (size_t)(t + 1) << 6);
      asm volatile("s_waitcnt vmcnt(4)" ::: "memory");
    } else {
      asm volatile("s_waitcnt vmcnt(0)" ::: "memory");
    }
    __builtin_amdgcn_s_barrier();
    __builtin_amdgcn_sched_barrier(0);
    __builtin_amdgcn_s_setprio(1);
    {
      const u16* Ac = lds + cur * 16384;
      const u16* Bc = lds + 32768 + cur * 16384;
#pragma unroll
      for (int s = 0; s < 2; ++s) {
        short8v af[4], bfr[4];
        const int kbx = (s * 32 + (lane >> 4) * 8) ^ ((lane & 7) * 8);
#pragma unroll
        for (int mi = 0; mi < 4; ++mi)
          af[mi] = *(const short8v*)&Ac[(wm + mi * 16 + (lane & 15)) * 64 + kbx];
#pragma unroll
        for (int ni = 0; ni < 4; ++ni)
          bfr[ni] = *(const short8v*)&Bc[(wn + ni * 16 + (lane & 15)) * 64 + kbx];
#pragma unroll
        for (int mi = 0; mi < 4; ++mi)
#pragma unroll
          for (int ni = 0; ni < 4; ++ni)
            acc[mi][ni] = __builtin_amdgcn_mfma_f32_16x16x32_bf16(
                af[mi], bfr[ni], acc[mi][ni], 0, 0, 0);
      }
    }
    __builtin_amdgcn_s_setprio(0);
    __builtin_amdgcn_sched_barrier(0);
    __builtin_amdgcn_s_barrier();
    cur ^= 1;
  }
#undef STAGE

#pragma unroll
  for (int mi = 0; mi < 4; ++mi) {
#pragma unroll
    for (int ni = 0; ni < 4; ++ni) {
      const int cc = n0 + wn + ni * 16 + (lane & 15);
      const int rloc = wm + mi * 16 + (lane >> 4) * 4;
#pragma unroll
      for (int j = 0; j < 4; ++j) {
        float v = fmaxf(acc[mi][ni][j] * SC[cc] + TB[cc], 0.f);
        C[(size_t)(m0l + rloc + j) * Nn + cc] = f2b(v);
      }
    }
  }
}

// ---------- GEMM2: 128x128 bf16 MFMA GEMM, 1024 threads (R12, proven) ----------
// 64KB dbuf -> 2 blocks/CU -> 8 waves/SIMD. Counted vmcnt(2); XOR + XCD swizzle.
// EPI 1: C(f32)[r_glob][c] = acc + B2f[c] + xres[r_glob][c]  (r_glob < Mreal)
template <int EPI>
__global__ __launch_bounds__(1024) void k_gemm(
    const u16* __restrict__ A, const u16* __restrict__ Apatch,
    const u16* __restrict__ BT, void* __restrict__ C,
    const float* __restrict__ SC, const float* __restrict__ TB,
    const float* __restrict__ B2f, const float* __restrict__ xres,
    int m0g_base, int Mreal, int nby, int Nn, int K) {
  __shared__ __align__(16) u16 As[2][128 * 64];
  __shared__ __align__(16) u16 Bs[2][128 * 64];
  const int tid = threadIdx.x;
  const int wave = tid >> 6, lane = tid & 63;

  const int nwg = gridDim.x;
  const int q = nwg >> 3, r = nwg & 7;
  const int xcd = blockIdx.x & 7;
  const int wid = (xcd < r ? xcd * (q + 1) : r * (q + 1) + (xcd - r) * q)
                  + (blockIdx.x >> 3);
  const int bx = wid / nby, by = wid - bx * nby;

  const int m0l = bx * 128;
  const int m0g = m0g_base + m0l;
  const int n0 = by * 128;
  const int wm = (wave >> 2) * 32, wn = (wave & 3) * 32;

  const bool patch = (Apatch != nullptr) && (m0g + 128 > Mreal);
  const u16* Ab = patch ? Apatch : A + (size_t)m0l * K;

  f32x4 acc[2][2] = {};

  const int srow = wave * 8 + (lane >> 3);
  const int scolx = (((lane & 7) ^ (lane >> 3)) * 8);
  const int ldst = srow * 64 + (lane & 7) * 8;
  const u16* ga = Ab + (size_t)srow * K + scolx;
  const u16* gb = BT + (size_t)(n0 + srow) * K + scolx;

#define STAGE(buf, kt)                                                    \
  {                                                                       \
    gload16(ga + (kt), &As[buf][ldst]);                                   \
    gload16(gb + (kt), &Bs[buf][ldst]);                                   \
  }

  const int nt = K >> 6;
  STAGE(0, 0);
  int cur = 0;
  for (int t = 0; t < nt; ++t) {
    if (t + 1 < nt) {
      STAGE(cur ^ 1, (size_t)(t + 1) << 6);
      asm volatile("s_waitcnt vmcnt(2)" ::: "memory");
    } else {
      asm volatile("s_waitcnt vmcnt(0)" ::: "memory");
    }
    __builtin_amdgcn_s_barrier();
    __builtin_amdgcn_sched_barrier(0);
    __builtin_amdgcn_s_setprio(1);
    {
      const u16* Ac = &As[cur][0];
      const u16* Bc = &Bs[cur][0];
#pragma unroll
      for (int s = 0; s < 2; ++s) {
        short8v af[2], bfr[2];
        const int kbx = (s * 32 + (lane >> 4) * 8) ^ ((lane & 7) * 8);
#pragma unroll
        for (int mi = 0; mi < 2; ++mi)
          af[mi] = *(const short8v*)&Ac[(wm + mi * 16 + (lane & 15)) * 64 + kbx];
#pragma unroll
        for (int ni = 0; ni < 2; ++ni)
          bfr[ni] = *(const short8v*)&Bc[(wn + ni * 16 + (lane & 15)) * 64 + kbx];
#pragma unroll
        for (int mi = 0; mi < 2; ++mi)
#pragma unroll
          for (int ni = 0; ni < 2; ++ni)
            acc[mi][ni] = __builtin_amdgcn_mfma_f32_16x16x32_bf16(
                af[mi], bfr[ni], acc[mi][ni], 0, 0, 0);
      }
    }
    __builtin_amdgcn_s_setprio(0);
    __builtin_amdgcn_sched_barrier(0);
    __builtin_amdgcn_s_barrier();
    cur ^= 1;
  }
#undef STAGE

#pragma unroll
  for (int mi = 0; mi < 2; ++mi) {
#pragma unroll
    for (int ni = 0; ni < 2; ++ni) {
      const int cc = n0 + wn + ni * 16 + (lane & 15);
      const int rloc = wm + mi * 16 + (lane >> 4) * 4;
#pragma unroll
      for (int j = 0; j < 4; ++j) {
        float v = acc[mi][ni][j];
        if (EPI == 0) {
          v = fmaxf(v * SC[cc] + TB[cc], 0.f);
          ((u16*)C)[(size_t)(m0l + rloc + j) * Nn + cc] = f2b(v);
        } else {
          const int rg = m0g + rloc + j;
          if (rg < Mreal) {
            v += B2f[cc] + xres[(size_t)rg * Nn + cc];
            ((float*)C)[(size_t)rg * Nn + cc] = v;
          }
        }
      }
    }
  }
}

// ---------------------------------------------------------------------------
extern "C" void kernel_launch(void* const* d_in, const int* in_sizes, int n_in,
                              void* d_out, int out_size, void* d_ws, size_t ws_size,
                              hipStream_t stream) {
  const float* x   = (const float*)d_in[0];
  const int* ei    = (const int*)d_in[1];
  const float* tin = (const float*)d_in[3];
  const float* W1  = (const float*)d_in[4];
  const float* b1  = (const float*)d_in[5];
  const float* gam = (const float*)d_in[6];
  const float* bet = (const float*)d_in[7];
  const float* mea = (const float*)d_in[8];
  const float* var = (const float*)d_in[9];
  const float* W2  = (const float*)d_in[10];
  const float* b2  = (const float*)d_in[11];
  float* dout = (float*)d_out;

  const int n = in_sizes[2];        // 10000 nodes
  const int E = in_sizes[1] / 2;    // 100000 edges
  const int D = in_sizes[11];       // 768
  const int H = in_sizes[5];        // 1536
  const int MPad = ((n + 255) / 256) * 256;  // 10240 (256-aligned)
  const int NBLK = MPad / 256;               // 40 (256-row chunks)
  const int PB0 = MPad - 256;                // first row of the crossing block

  // d_out aliasing plan: abuf = bytes [0,2nD) bf16 agg; xb = [2nD,4nD) bf16 x
  // (dead after k_agg). GEMM2 writes fp32 rows high->low; never clobbers
  // not-yet-consumed abuf rows.
  u16* abuf = (u16*)d_out;
  u16* xb   = (u16*)d_out + (size_t)n * D;

  // workspace layout (256B-aligned slabs)
  uint8_t* w = (uint8_t*)d_ws;
  auto alloc = [&](size_t bytes) {
    uint8_t* p = w; w += (bytes + 255) & ~(size_t)255; return p;
  };
  int*   deg     = (int*)alloc((size_t)n * 4);
  int*   rowptr  = (int*)alloc((size_t)(n + 1) * 4);
  int*   cursor  = (int*)alloc((size_t)n * 4);
  int*   csr_src = (int*)alloc((size_t)E * 4);
  float* SC      = (float*)alloc((size_t)H * 4);
  float* TB      = (float*)alloc((size_t)H * 4);
  float* B2f     = (float*)alloc((size_t)D * 4);
  float* tf      = (float*)alloc(8);                 // t, t*log2e
  u16*   W1T     = (u16*)alloc((size_t)H * D * 2);   // [H][D] bf16
  u16*   W2T     = (u16*)alloc((size_t)D * H * 2);   // [D][H] bf16
  u16*   Apatch  = (u16*)alloc((size_t)256 * D * 2); // last-block A tile (256 rows)
  u16*   hbuf    = (u16*)w;                           // rest of ws

  // how many 256-row blocks of h fit in remaining workspace
  const size_t used = (size_t)(w - (uint8_t*)d_ws);
  const size_t per_blk = (size_t)256 * H * 2;
  size_t avail = (ws_size > used) ? (ws_size - used) : 0;
  int cblk = (int)(avail / per_blk);
  if (cblk < 1) cblk = 1;
  if (cblk > NBLK) cblk = NBLK;

  const int padwords = (MPad - n) * D / 2;  // zero pad rows of Apatch (u32 words)
  const int initN = (n > padwords) ? n : padwords;

  // fused prologue dispatch
  const int nb_init = (initN + 255) / 256;
  const int nb_prep = (H + 255) / 256;
  const int nb_t1 = (H / 32) * (D / 32);
  const int nb_t2 = (D / 32) * (H / 32);
  const int nb_cvt = 1024;
  const int nmisc = nb_init + nb_prep + nb_t1 + nb_t2 + nb_cvt;

  // allow 128 KB dynamic LDS for the 256-tile GEMM (idempotent, capture-safe)
  static bool attr_set = false;
  if (!attr_set) {
    hipFuncSetAttribute((const void*)k_gemm256,
                        hipFuncAttributeMaxDynamicSharedMemorySize, 131072);
    attr_set = true;
  }

  k_misc<<<nmisc, 256, 0, stream>>>(
      deg, (uint32_t*)(Apatch + (size_t)(n - PB0) * D), n, padwords,
      b1, gam, bet, mea, var, b2, tin, SC, TB, B2f, tf, H, D,
      W1, W1T, W2, W2T, x, xb, n * D / 4,
      nb_init, nb_prep, nb_t1, nb_t2, nb_cvt);
  k_hist<<<(E + 255) / 256, 256, 0, stream>>>(ei, deg, E);
  k_scan<<<1, 1024, 0, stream>>>(deg, rowptr, cursor, n, E);
  k_scatter<<<(E + 255) / 256, 256, 0, stream>>>(ei, cursor, csr_src, E);
  k_agg<<<n, 192, 0, stream>>>((const uint32_t*)xb, x, rowptr, csr_src, tf,
                               abuf, Apatch, PB0, D);

  // chunks high -> low (see aliasing note above); chunks are 256-row blocks
  int b0 = ((NBLK - 1) / cblk) * cblk;
  for (; b0 >= 0; b0 -= cblk) {
    const int nb = (cblk < NBLK - b0) ? cblk : (NBLK - b0);
    // h[nb*256][H] = bf16(relu(BN(A @ W1))) ; A = abuf rows (+patch last blk)
    k_gemm256<<<nb * (H / 256), 1024, 131072, stream>>>(
        abuf + (size_t)b0 * 256 * D, Apatch, W1T, hbuf,
        SC, TB, b0 * 256, n, H / 256, H, D);
    // dout[rows] = fp32( h @ W2 + b2 + x )  (128-row tiles over the chunk)
    k_gemm<1><<<(nb * 2) * (D / 128), 1024, 0, stream>>>(
        hbuf, nullptr, W2T, dout,
        nullptr, nullptr, B2f, x, b0 * 256, n, D / 128, D, H);
  }
}